// Round 12
// baseline (101.607 us; speedup 1.0000x reference)
//
#include <hip/hip_runtime.h>

// TopKGate via split-precision f16 MFMA (no fp32 MFMA on CDNA4):
//   x = xh + xl/4096, w = wh + wl/4096 (f16 planes, lo pre-scaled x4096)
//   logits = xh*wh + (xh*wl' + xl'*wh)/4096
// R12: BM=32, 512 blocks (2/CU). 4 waves K-split a BK=64 chunk (wave kh owns
// one 16-k slice, full 64 experts -> x CVT once per element). 3-deep LDS
// staging via global_load_lds with counted vmcnt + raw s_barrier (never
// drain-0 in loop). Epilogue reduces the 4 K-partials in LDS, then the
// 10x-proven softmax/top-2/aux chain.

typedef __attribute__((ext_vector_type(8))) _Float16 half8;
typedef __attribute__((ext_vector_type(16))) float f32x16;

constexpr int DD   = 2048;
constexpr int EE   = 64;
constexpr int BM   = 32;         // tokens per block
constexpr int BK   = 64;         // k per staged chunk
constexpr int NCH  = DD / BK;    // 32 chunks
constexpr int NBUF = 3;

#define BAR()   asm volatile("s_barrier" ::: "memory")
#define WVM(N)  asm volatile("s_waitcnt vmcnt(" #N ")" ::: "memory")

// ---- pre-kernel: split + transpose + swizzle Wg -> whT/wlT [64][2048] ----
__global__ __launch_bounds__(64) void wsplit_kernel(
    const float* __restrict__ Wg, _Float16* __restrict__ whT,
    _Float16* __restrict__ wlT)
{
    const int n  = threadIdx.x;          // expert 0..63
    const int k0 = blockIdx.x * 64;      // 32 blocks
    _Float16 hh[64], ll[64];
#pragma unroll
    for (int kk = 0; kk < 64; ++kk) {
        float v = Wg[(size_t)(k0 + kk) * EE + n];   // coalesced 256B/wave
        _Float16 h = (_Float16)v;
        hh[kk] = h;
        ll[kk] = (_Float16)((v - (float)h) * 4096.f);
    }
    const int swb = n & 7;               // 8-half block swizzle (matches reader)
#pragma unroll
    for (int bp = 0; bp < 8; ++bp) {
        const int bs = bp ^ swb;
        *(half8*)&whT[(size_t)n * DD + k0 + bp * 8] = *(const half8*)&hh[bs * 8];
        *(half8*)&wlT[(size_t)n * DD + k0 + bp * 8] = *(const half8*)&ll[bs * 8];
    }
}

__global__ __launch_bounds__(256) void gate_kernel(
    const float* __restrict__ x, const _Float16* __restrict__ whT,
    const _Float16* __restrict__ wlT,
    float* __restrict__ gate_out, float* __restrict__ idx_out,
    float* __restrict__ pSum, float* __restrict__ pCnt)
{
    __shared__ __align__(16) union {
        struct {
            float    xs[NBUF][BM][BK];       // 3 x 8 KB
            _Float16 wsb[NBUF][2][EE][BK];   // 3 x 16 KB   -> 72 KB total
        } st;
        struct { float logits[4][BM][68]; float auxsm[2][4][64]; } ep; // 36.8 KB
    } sm;

    const int tid  = threadIdx.x;
    const int wv   = tid >> 6;           // kh: k-slice within chunk (0..3)
    const int lane = tid & 63;
    const size_t tok0 = (size_t)blockIdx.x * BM;

    // stage chunk c into buffer buf: 6 global_load_lds per thread (linear dest)
    auto stage = [&](int buf, int c) {
        const float* xg = x + tok0 * DD + c * BK;
#pragma unroll
        for (int r = 0; r < 2; ++r) {
            int slot = tid + r * 256;            // float4 slot 0..511
            int row  = slot >> 4;                // 0..31
            int cb   = (slot & 15) << 4;         // byte in 256B row
            int sb   = cb ^ ((row & 7) << 5);    // source-swizzled byte
            __builtin_amdgcn_global_load_lds(
                xg + (size_t)row * DD + (sb >> 2),
                &sm.st.xs[buf][row][(slot & 15) << 2], 16, 0, 0);
        }
#pragma unroll
        for (int p = 0; p < 2; ++p) {
            const _Float16* wg = (p ? wlT : whT) + c * BK;
#pragma unroll
            for (int r = 0; r < 2; ++r) {
                int slot = tid + r * 256;        // 16B slot 0..511
                int n = slot >> 3, j = slot & 7;
                __builtin_amdgcn_global_load_lds(
                    wg + (size_t)n * DD + j * 8,
                    &sm.st.wsb[buf][p][n][j * 8], 16, 0, 0);
            }
        }
    };

    f32x16 acc1, acc2, acc3, acc4;
#pragma unroll
    for (int e = 0; e < 16; ++e) { acc1[e] = 0.f; acc2[e] = 0.f;
                                   acc3[e] = 0.f; acc4[e] = 0.f; }

    const int arow = lane & 31;                  // token row / expert row
    const int kg   = lane >> 5;                  // k-group
    const int sw   = (lane & 7) << 3;            // 8-elem block swizzle
    const int base = (wv * 16 + kg * 8) ^ sw;    // swizzled 8-elem offset

    auto compute = [&](int buf) {
        float4 xa = *(const float4*)&sm.st.xs[buf][arow][base];
        float4 xb = *(const float4*)&sm.st.xs[buf][arow][base + 4];
        half8 ah, al;
#define CVT(E, V)                                                              \
        { _Float16 h = (_Float16)(V); ah[E] = h;                               \
          al[E] = (_Float16)(((V) - (float)h) * 4096.f); }
        CVT(0, xa.x) CVT(1, xa.y) CVT(2, xa.z) CVT(3, xa.w)
        CVT(4, xb.x) CVT(5, xb.y) CVT(6, xb.z) CVT(7, xb.w)
#undef CVT
        half8 bh0 = *(const half8*)&sm.st.wsb[buf][0][arow][base];
        half8 bl0 = *(const half8*)&sm.st.wsb[buf][1][arow][base];
        half8 bh1 = *(const half8*)&sm.st.wsb[buf][0][32 + arow][base];
        half8 bl1 = *(const half8*)&sm.st.wsb[buf][1][32 + arow][base];
        acc1 = __builtin_amdgcn_mfma_f32_32x32x16_f16(ah, bh0, acc1, 0, 0, 0);
        acc2 = __builtin_amdgcn_mfma_f32_32x32x16_f16(ah, bl0, acc2, 0, 0, 0);
        acc2 = __builtin_amdgcn_mfma_f32_32x32x16_f16(al, bh0, acc2, 0, 0, 0);
        acc3 = __builtin_amdgcn_mfma_f32_32x32x16_f16(ah, bh1, acc3, 0, 0, 0);
        acc4 = __builtin_amdgcn_mfma_f32_32x32x16_f16(ah, bl1, acc4, 0, 0, 0);
        acc4 = __builtin_amdgcn_mfma_f32_32x32x16_f16(al, bh1, acc4, 0, 0, 0);
    };

    // prologue: 3 stages in flight; wait oldest, never drain to 0 in loop
    stage(0, 0); stage(1, 1); stage(2, 2);
    WVM(12); BAR();

    int buf = 0;
#pragma unroll 1
    for (int c = 0; c < NCH; ++c) {
        compute(buf);
        BAR();                                   // all waves done reading buf
        if (c + 3 < NCH)       { stage(buf, c + 3); WVM(12); }
        else if (c + 3 == NCH) { WVM(6); }
        else if (c + 2 == NCH) { WVM(0); }
        BAR();                                   // buf (c+1)%3 ready for all
        buf = (buf == NBUF - 1) ? 0 : buf + 1;
    }

    // ---- K-partials -> LDS (verified m74/m101 C layout), combine planes ----
    __syncthreads();
    const float inv = 1.f / 4096.f;
#pragma unroll
    for (int e = 0; e < 16; ++e) {
        const int lr = (e & 3) + ((e >> 2) << 3) + ((lane >> 5) << 2); // token
        sm.ep.logits[wv][lr][arow]      = acc1[e] + acc2[e] * inv;
        sm.ep.logits[wv][lr][32 + arow] = acc3[e] + acc4[e] * inv;
    }
    __syncthreads();

    // ---- epilogue: wave wv -> tokens [wv*8, wv*8+8); lane = expert ----
    float sumP_acc = 0.f;
    float cnt_acc  = 0.f;
#pragma unroll 1
    for (int tt = 0; tt < 8; ++tt) {
        const int tl = wv * 8 + tt;
        const size_t t = tok0 + tl;
        float v = (sm.ep.logits[0][tl][lane] + sm.ep.logits[1][tl][lane])
                + (sm.ep.logits[2][tl][lane] + sm.ep.logits[3][tl][lane]);

        float m = v;
#pragma unroll
        for (int off = 32; off; off >>= 1) m = fmaxf(m, __shfl_xor(m, off, 64));
        float p = expf(v - m);
        float s = p;
#pragma unroll
        for (int off = 32; off; off >>= 1) s += __shfl_xor(s, off, 64);
        float prob = p / s;
        sumP_acc += prob;

        // top-1 (ties -> lowest index, matches lax.top_k)
        float bv = prob; int bi = lane;
#pragma unroll
        for (int off = 32; off; off >>= 1) {
            float ov = __shfl_xor(bv, off, 64);
            int   oi = __shfl_xor(bi, off, 64);
            if (ov > bv || (ov == bv && oi < bi)) { bv = ov; bi = oi; }
        }
        // top-2
        float v2 = (lane == bi) ? -1.f : prob;
        float bv2 = v2; int bi2 = lane;
#pragma unroll
        for (int off = 32; off; off >>= 1) {
            float ov = __shfl_xor(bv2, off, 64);
            int   oi = __shfl_xor(bi2, off, 64);
            if (ov > bv2 || (ov == bv2 && oi < bi2)) { bv2 = ov; bi2 = oi; }
        }

        float denom = bv + bv2;
        float g1 = bv / denom, g2 = bv2 / denom;
        float g = (lane == bi) ? g1 : ((lane == bi2) ? g2 : 0.f);
        gate_out[t * EE + lane] = g;
        if (lane == 0) {
            idx_out[2 * t]     = (float)bi;
            idx_out[2 * t + 1] = (float)bi2;
        }
        cnt_acc += (lane == bi)  ? 1.f : 0.f;
        cnt_acc += (lane == bi2) ? 1.f : 0.f;
    }

    // ---- per-block aux partials (deterministic) ----
    sm.ep.auxsm[0][wv][lane] = sumP_acc;
    sm.ep.auxsm[1][wv][lane] = cnt_acc;
    __syncthreads();
    if (wv == 0) {
        float sp = 0.f, c2 = 0.f;
#pragma unroll
        for (int w = 0; w < 4; ++w) {
            sp += sm.ep.auxsm[0][w][lane];
            c2 += sm.ep.auxsm[1][w][lane];
        }
        pSum[(size_t)blockIdx.x * 64 + lane] = sp;
        pCnt[(size_t)blockIdx.x * 64 + lane] = c2;
    }
}

// parallel aux reduction: 1024 threads (16 waves), 4-deep ILP + LDS reduce
__global__ __launch_bounds__(1024) void aux_kernel(
    const float* __restrict__ pSum, const float* __restrict__ pCnt,
    float* __restrict__ aux_out, int nblocks, float scale)
{
    const int tid  = threadIdx.x;
    const int wv   = tid >> 6;       // 0..15
    const int lane = tid & 63;       // = expert id
    __shared__ float smem[2][16][64];

    float sp[4] = {0.f, 0.f, 0.f, 0.f};
    float cc[4] = {0.f, 0.f, 0.f, 0.f};
    for (int b = wv * 4; b < nblocks; b += 64) {
#pragma unroll
        for (int u = 0; u < 4; ++u) {
            sp[u] += pSum[(size_t)(b + u) * 64 + lane];
            cc[u] += pCnt[(size_t)(b + u) * 64 + lane];
        }
    }
    smem[0][wv][lane] = (sp[0] + sp[1]) + (sp[2] + sp[3]);
    smem[1][wv][lane] = (cc[0] + cc[1]) + (cc[2] + cc[3]);
    __syncthreads();
    if (wv == 0) {
        float SP = 0.f, C = 0.f;
#pragma unroll
        for (int w = 0; w < 16; ++w) {
            SP += smem[0][w][lane];
            C  += smem[1][w][lane];
        }
        float prod = SP * C;
#pragma unroll
        for (int off = 32; off; off >>= 1) prod += __shfl_xor(prod, off, 64);
        if (lane == 0) aux_out[0] = prod * scale;
    }
}

extern "C" void kernel_launch(void* const* d_in, const int* in_sizes, int n_in,
                              void* d_out, int out_size, void* d_ws, size_t ws_size,
                              hipStream_t stream) {
    const float* x  = (const float*)d_in[0];
    const float* Wg = (const float*)d_in[1];
    const int T = in_sizes[0] / DD;          // 16384

    float* out      = (float*)d_out;
    float* gate_out = out;                                // T*64
    float* idx_out  = out + (size_t)T * EE;               // T*2 (as float)
    float* aux_out  = idx_out + (size_t)T * 2;            // 1

    const int nblocks = T / BM;                           // 512
    _Float16* whT = (_Float16*)d_ws;                      // 256 KB
    _Float16* wlT = whT + (size_t)EE * DD;                // 256 KB
    float* pSum = (float*)(wlT + (size_t)EE * DD);        // nblocks*64
    float* pCnt = pSum + (size_t)nblocks * 64;            // nblocks*64

    wsplit_kernel<<<DD / 64, 64, 0, stream>>>(Wg, whT, wlT);
    gate_kernel<<<nblocks, 256, 0, stream>>>(x, whT, wlT,
                                             gate_out, idx_out, pSum, pCnt);

    const float scale = (float)EE / ((float)T * (float)T);
    aux_kernel<<<1, 1024, 0, stream>>>(pSum, pCnt, aux_out, nblocks, scale);
}

// Round 13
// 55.818 us; speedup vs baseline: 1.8203x; 1.8203x over previous
//
#include <hip/hip_runtime.h>

// TopKGate via split-precision f16 MFMA (no fp32 MFMA on CDNA4):
//   x = xh + xl/4096, w = wh + wl/4096 (f16 planes, lo pre-scaled x4096)
//   logits = xh*wh + (xh*wl' + xl'*wh)/4096
// R13: BM=16, grid 1024 (4 blocks/CU, 16 waves/CU). mfma_f32_16x16x32_f16.
// Waves: (kh: k-half of BK=64) x (nh: expert-half). NBUF=2, LDS 40 KB.
// w pre-split into chunk-major planes [kc][n][64] (pre-swizzled) -> gate's
// w staging is a linear coalesced 16 KB global_load_lds copy per chunk.

typedef __attribute__((ext_vector_type(8))) _Float16 half8;
typedef __attribute__((ext_vector_type(4))) float f32x4;

constexpr int DD   = 2048;
constexpr int EE   = 64;
constexpr int BM   = 16;         // tokens per block
constexpr int BK   = 64;         // k per staged chunk
constexpr int NCH  = DD / BK;    // 32 chunks

#define BAR()   asm volatile("s_barrier" ::: "memory")
#define WVM(N)  asm volatile("s_waitcnt vmcnt(" #N ")" ::: "memory")

// ---- pre-kernel: Wg [2048][64] -> chunk-major swizzled f16 planes ----
// whTc/wlTc layout: [kc][n][64 halves], 8-half block bp stored at bp^(n&7).
__global__ __launch_bounds__(256) void wsplit_kernel(
    const float* __restrict__ Wg, _Float16* __restrict__ whTc,
    _Float16* __restrict__ wlTc)
{
    __shared__ float xl[64][68];
    const int tid = threadIdx.x;
    const int kc  = blockIdx.x;          // 32 blocks, 64 k's each
    const int k0  = kc * 64;

#pragma unroll
    for (int r = 0; r < 4; ++r) {
        int slot = tid + r * 256;        // float4 slot 0..1023
        int row = slot >> 4, c4 = (slot & 15) << 2;
        *(float4*)&xl[row][c4] = *(const float4*)&Wg[(size_t)(k0 + row) * EE + c4];
    }
    __syncthreads();

    const int n  = tid >> 2;             // expert 0..63
    const int kq = tid & 3;              // 16-k quarter
    _Float16 hh[16], ll[16];
#pragma unroll
    for (int i = 0; i < 16; ++i) {
        float v = xl[kq * 16 + i][n];
        _Float16 h = (_Float16)v;
        hh[i] = h;
        ll[i] = (_Float16)((v - (float)h) * 4096.f);
    }
    const size_t rb = (size_t)kc * 4096 + n * 64;
#pragma unroll
    for (int j = 0; j < 2; ++j) {
        int bp  = kq * 2 + j;
        int pos = (bp ^ (n & 7)) * 8;
        *(half8*)&whTc[rb + pos] = *(const half8*)&hh[j * 8];
        *(half8*)&wlTc[rb + pos] = *(const half8*)&ll[j * 8];
    }
}

__global__ __launch_bounds__(256, 4) void gate_kernel(
    const float* __restrict__ x, const _Float16* __restrict__ whTc,
    const _Float16* __restrict__ wlTc,
    float* __restrict__ gate_out, float* __restrict__ idx_out,
    float* __restrict__ pSum, float* __restrict__ pCnt)
{
    __shared__ __align__(16) union {
        struct {
            float    xs[2][BM][BK];      // 2 x 4 KB
            _Float16 wsb[2][2][EE][BK];  // 2 x 16 KB  -> 40 KB total
        } st;
        struct { float logits[2][BM][68]; float auxsm[2][4][64]; } ep;
    } sm;

    const int tid  = threadIdx.x;
    const int wv   = tid >> 6;
    const int lane = tid & 63;
    const int kh   = wv & 1;             // k-half of chunk (32 k's)
    const int nh   = wv >> 1;            // expert-half (32 experts)
    const size_t tok0 = (size_t)blockIdx.x * BM;

    // stage chunk c -> buffer buf: 5 global_load_lds per thread, linear dests
    auto stage = [&](int buf, int c) {
        {   // x: 16 rows x 16 float4 slots, source-XOR swizzled
            int slot = tid;              // 0..255
            int row  = slot >> 4;
            int cb   = (slot & 15) << 4;
            int sb   = cb ^ ((row & 7) << 5);
            __builtin_amdgcn_global_load_lds(
                x + (tok0 + row) * DD + c * BK + (sb >> 2),
                &sm.st.xs[buf][row][(slot & 15) << 2], 16, 0, 0);
        }
#pragma unroll
        for (int p = 0; p < 2; ++p) {    // w planes: fully linear 8 KB each
            const _Float16* wg = (p ? wlTc : whTc) + (size_t)c * 4096;
            _Float16* dst = &sm.st.wsb[buf][p][0][0];
#pragma unroll
            for (int r = 0; r < 2; ++r) {
                int slot = tid + r * 256;            // 8-half slot 0..511
                __builtin_amdgcn_global_load_lds(
                    wg + slot * 8, dst + slot * 8, 16, 0, 0);
            }
        }
    };

    f32x4 accH0 = {0.f,0.f,0.f,0.f}, accL0 = {0.f,0.f,0.f,0.f};
    f32x4 accH1 = {0.f,0.f,0.f,0.f}, accL1 = {0.f,0.f,0.f,0.f};

    const int arow = lane & 15;                  // token row
    const int kg   = lane >> 4;                  // k-group 0..3
    const int k8   = kh * 32 + kg * 8;           // logical 8-float k block
    const int ax   = k8 ^ ((arow & 7) << 3);     // swizzled x float index
    const int e0   = nh * 32 + (lane & 15);      // expert col, tile 0
    const int e1   = e0 + 16;                    // expert col, tile 1
    const int b0   = k8 ^ ((e0 & 7) << 3);       // swizzled w half index
    const int b1   = k8 ^ ((e1 & 7) << 3);

    auto compute = [&](int buf) {
        float4 xa = *(const float4*)&sm.st.xs[buf][arow][ax];
        float4 xb = *(const float4*)&sm.st.xs[buf][arow][ax + 4];
        half8 ah, al;
#define CVT(E, V)                                                              \
        { _Float16 h = (_Float16)(V); ah[E] = h;                               \
          al[E] = (_Float16)(((V) - (float)h) * 4096.f); }
        CVT(0, xa.x) CVT(1, xa.y) CVT(2, xa.z) CVT(3, xa.w)
        CVT(4, xb.x) CVT(5, xb.y) CVT(6, xb.z) CVT(7, xb.w)
#undef CVT
        half8 bh0 = *(const half8*)&sm.st.wsb[buf][0][e0][b0];
        half8 bl0 = *(const half8*)&sm.st.wsb[buf][1][e0][b0];
        half8 bh1 = *(const half8*)&sm.st.wsb[buf][0][e1][b1];
        half8 bl1 = *(const half8*)&sm.st.wsb[buf][1][e1][b1];
        accH0 = __builtin_amdgcn_mfma_f32_16x16x32_f16(ah, bh0, accH0, 0, 0, 0);
        accL0 = __builtin_amdgcn_mfma_f32_16x16x32_f16(ah, bl0, accL0, 0, 0, 0);
        accL0 = __builtin_amdgcn_mfma_f32_16x16x32_f16(al, bh0, accL0, 0, 0, 0);
        accH1 = __builtin_amdgcn_mfma_f32_16x16x32_f16(ah, bh1, accH1, 0, 0, 0);
        accL1 = __builtin_amdgcn_mfma_f32_16x16x32_f16(ah, bl1, accL1, 0, 0, 0);
        accL1 = __builtin_amdgcn_mfma_f32_16x16x32_f16(al, bh1, accL1, 0, 0, 0);
    };

    // prologue: 2 stages in flight; wait own oldest stage, then join
    stage(0, 0);
    stage(1, 1);
    WVM(5); BAR();

#pragma unroll 1
    for (int c = 0; c < NCH; ++c) {
        const int buf = c & 1;
        compute(buf);
        BAR();                                   // all waves done reading buf
        if (c + 2 < NCH)       { stage(buf, c + 2); WVM(5); }
        else if (c + 2 == NCH) { WVM(0); }       // drain last pending stage
        BAR();                                   // next buffer ready for all
    }

    // ---- C -> logits LDS (m89-verified layout), combine planes ----
    __syncthreads();
    const float inv = 1.f / 4096.f;
#pragma unroll
    for (int e = 0; e < 4; ++e) {
        const int row = (lane >> 4) * 4 + e;     // token 0..15
        sm.ep.logits[kh][row][e0] = accH0[e] + accL0[e] * inv;
        sm.ep.logits[kh][row][e1] = accH1[e] + accL1[e] * inv;
    }
    __syncthreads();

    // ---- epilogue: wave wv -> tokens [wv*4, wv*4+4); lane = expert ----
    float sumP_acc = 0.f;
    float cnt_acc  = 0.f;
#pragma unroll 1
    for (int tt = 0; tt < 4; ++tt) {
        const int tl = wv * 4 + tt;
        const size_t t = tok0 + tl;
        float v = sm.ep.logits[0][tl][lane] + sm.ep.logits[1][tl][lane];

        float m = v;
#pragma unroll
        for (int off = 32; off; off >>= 1) m = fmaxf(m, __shfl_xor(m, off, 64));
        float p = expf(v - m);
        float s = p;
#pragma unroll
        for (int off = 32; off; off >>= 1) s += __shfl_xor(s, off, 64);
        float prob = p / s;
        sumP_acc += prob;

        // top-1 (ties -> lowest index, matches lax.top_k)
        float bv = prob; int bi = lane;
#pragma unroll
        for (int off = 32; off; off >>= 1) {
            float ov = __shfl_xor(bv, off, 64);
            int   oi = __shfl_xor(bi, off, 64);
            if (ov > bv || (ov == bv && oi < bi)) { bv = ov; bi = oi; }
        }
        // top-2
        float v2 = (lane == bi) ? -1.f : prob;
        float bv2 = v2; int bi2 = lane;
#pragma unroll
        for (int off = 32; off; off >>= 1) {
            float ov = __shfl_xor(bv2, off, 64);
            int   oi = __shfl_xor(bi2, off, 64);
            if (ov > bv2 || (ov == bv2 && oi < bi2)) { bv2 = ov; bi2 = oi; }
        }

        float denom = bv + bv2;
        float g1 = bv / denom, g2 = bv2 / denom;
        float g = (lane == bi) ? g1 : ((lane == bi2) ? g2 : 0.f);
        gate_out[t * EE + lane] = g;
        if (lane == 0) {
            idx_out[2 * t]     = (float)bi;
            idx_out[2 * t + 1] = (float)bi2;
        }
        cnt_acc += (lane == bi)  ? 1.f : 0.f;
        cnt_acc += (lane == bi2) ? 1.f : 0.f;
    }

    // ---- per-block aux partials (deterministic) ----
    sm.ep.auxsm[0][wv][lane] = sumP_acc;
    sm.ep.auxsm[1][wv][lane] = cnt_acc;
    __syncthreads();
    if (wv == 0) {
        float sp = 0.f, c2 = 0.f;
#pragma unroll
        for (int w = 0; w < 4; ++w) {
            sp += sm.ep.auxsm[0][w][lane];
            c2 += sm.ep.auxsm[1][w][lane];
        }
        pSum[(size_t)blockIdx.x * 64 + lane] = sp;
        pCnt[(size_t)blockIdx.x * 64 + lane] = c2;
    }
}

// parallel aux reduction: 1024 threads (16 waves), 4-deep ILP + LDS reduce
__global__ __launch_bounds__(1024) void aux_kernel(
    const float* __restrict__ pSum, const float* __restrict__ pCnt,
    float* __restrict__ aux_out, int nblocks, float scale)
{
    const int tid  = threadIdx.x;
    const int wv   = tid >> 6;       // 0..15
    const int lane = tid & 63;       // = expert id
    __shared__ float smem[2][16][64];

    float sp[4] = {0.f, 0.f, 0.f, 0.f};
    float cc[4] = {0.f, 0.f, 0.f, 0.f};
    for (int b = wv * 4; b < nblocks; b += 64) {
#pragma unroll
        for (int u = 0; u < 4; ++u) {
            sp[u] += pSum[(size_t)(b + u) * 64 + lane];
            cc[u] += pCnt[(size_t)(b + u) * 64 + lane];
        }
    }
    smem[0][wv][lane] = (sp[0] + sp[1]) + (sp[2] + sp[3]);
    smem[1][wv][lane] = (cc[0] + cc[1]) + (cc[2] + cc[3]);
    __syncthreads();
    if (wv == 0) {
        float SP = 0.f, C = 0.f;
#pragma unroll
        for (int w = 0; w < 16; ++w) {
            SP += smem[0][w][lane];
            C  += smem[1][w][lane];
        }
        float prod = SP * C;
#pragma unroll
        for (int off = 32; off; off >>= 1) prod += __shfl_xor(prod, off, 64);
        if (lane == 0) aux_out[0] = prod * scale;
    }
}

extern "C" void kernel_launch(void* const* d_in, const int* in_sizes, int n_in,
                              void* d_out, int out_size, void* d_ws, size_t ws_size,
                              hipStream_t stream) {
    const float* x  = (const float*)d_in[0];
    const float* Wg = (const float*)d_in[1];
    const int T = in_sizes[0] / DD;          // 16384

    float* out      = (float*)d_out;
    float* gate_out = out;                                // T*64
    float* idx_out  = out + (size_t)T * EE;               // T*2 (as float)
    float* aux_out  = idx_out + (size_t)T * 2;            // 1

    const int nblocks = T / BM;                           // 1024
    _Float16* whTc = (_Float16*)d_ws;                     // 256 KB
    _Float16* wlTc = whTc + (size_t)EE * DD;              // 256 KB
    float* pSum = (float*)(wlTc + (size_t)EE * DD);       // 256 KB
    float* pCnt = pSum + (size_t)nblocks * 64;            // 256 KB

    wsplit_kernel<<<DD / 64, 256, 0, stream>>>(Wg, whTc, wlTc);
    gate_kernel<<<nblocks, 256, 0, stream>>>(x, whTc, wlTc,
                                             gate_out, idx_out, pSum, pCnt);

    const float scale = (float)EE / ((float)T * (float)T);
    aux_kernel<<<1, 1024, 0, stream>>>(pSum, pCnt, aux_out, nblocks, scale);
}